// Round 2
// baseline (1052.263 us; speedup 1.0000x reference)
//
#include <hip/hip_runtime.h>
#include <hip/hip_bf16.h>
#include <hip/hip_fp16.h>

typedef _Float16 f16;
typedef _Float16 f16x8 __attribute__((ext_vector_type(8)));
typedef float f32x4 __attribute__((ext_vector_type(4)));

#define SP 16384  // 128*128 spatial per batch
#define TPB 8     // tiles per persistent block (512 blocks * 8 = 4096 tiles)

// ---- transpose + cast weights to fp16, N-major: WT[n][k] = W[k][n] ----
__global__ void prep_weights(const float* __restrict__ Wq,
                             const float* __restrict__ Wkv,
                             const float* __restrict__ Wp,
                             f16* __restrict__ wqT,
                             f16* __restrict__ wkvT,
                             f16* __restrict__ wpT) {
  const int f = threadIdx.x;  // 0..511 feature (col of W)
  const int k = blockIdx.x;   // 0..255 input dim (row of W)
  wkvT[f * 256 + k] = (f16)Wkv[k * 512 + f];
  if (f < 256) {
    wqT[f * 256 + k] = (f16)Wq[k * 256 + f];
    wpT[f * 256 + k] = (f16)Wp[k * 256 + f];
  }
}

// Persistent fused kernel with cross-tile pipelining:
// while tile i's GEMM runs, tile i+1's x is loaded from HBM and packed to fp16
// in registers; written to LDS right after the post-GEMM barrier.
__global__ __launch_bounds__(512, 2) void fused_attn(
    const float* __restrict__ x,
    const float* __restrict__ bq,
    const float* __restrict__ bkv,
    const float* __restrict__ bp,
    const float* __restrict__ pos_bias,
    const f16* __restrict__ wqT,
    const f16* __restrict__ wkvT,
    const f16* __restrict__ wpT,
    float* __restrict__ out) {
  __shared__ f16 xs[5 * 16 * 256];  // 40 KB x-tile, swizzled byte ^= (row&7)<<4
  __shared__ f16 as[16 * 256];      // 8 KB attn-out tile

  const int tid = threadIdx.x;
  // staging role: row r (0..15), d-chunk q (0..31) -> d = 8q..8q+7
  const int r = tid & 15;
  const int q = tid >> 4;
  // compute role
  const int lane = tid & 63;
  const int w = tid >> 6;    // wave 0..7 -> heads 2w, 2w+1
  const int c = lane & 15;   // A-row / B-col / C-col
  const int g4 = lane >> 4;  // 0..3 (k-group; C rows 4g..4g+3)
  const int hA = 2 * w;

  // hoisted per-(head,c) scalars (tile-invariant)
  float bqv[2], bkb[2], bvb[2], bpv[2], pb[2][5];
#pragma unroll
  for (int j = 0; j < 2; ++j) {
    const int hj = hA + j;
    bqv[j] = bq[hj * 16 + c];
    bkb[j] = bkv[hj * 16 + c];
    bvb[j] = bkv[256 + hj * 16 + c];
    bpv[j] = bp[hj * 16 + c];
#pragma unroll
    for (int t = 0; t < 5; ++t) pb[j][t] = pos_bias[hj * 5 + t];
  }

  // hoisted weight row pointers
  const f16* wqp0 = wqT + (hA * 16 + c) * 256;
  const f16* wqp1 = wqT + ((hA + 1) * 16 + c) * 256;
  const f16* wkp0 = wkvT + (hA * 16 + c) * 256;
  const f16* wkp1 = wkvT + ((hA + 1) * 16 + c) * 256;
  const f16* wvp0 = wkvT + (256 + hA * 16 + c) * 256;
  const f16* wvp1 = wkvT + (256 + (hA + 1) * 16 + c) * 256;
  const f16* wpp0 = wpT + (hA * 16 + c) * 256;
  const f16* wpp1 = wpT + ((hA + 1) * 16 + c) * 256;

  const int gt = blockIdx.x * TPB;
  const char* lr = (const char*)xs;

  // ---- prologue: stage tile gt ----
  {
    const int b0 = gt >> 10, s00 = (gt & 1023) << 4;
    const float* xb = x + (size_t)b0 * (5 * 256 * SP) + s00 + r;
#pragma unroll
    for (int t = 0; t < 5; ++t) {
      float v[8];
#pragma unroll
      for (int j = 0; j < 8; ++j) v[j] = xb[(size_t)(t * 256 + 8 * q + j) * SP];
      f16x8 pk;
#pragma unroll
      for (int j = 0; j < 8; ++j) pk[j] = (f16)v[j];
      const int byte = (t << 13) + (((r << 9) + (q << 4)) ^ ((r & 7) << 4));
      *(f16x8*)((char*)xs + byte) = pk;
    }
  }
  __syncthreads();

  for (int i = 0; i < TPB; ++i) {
    const int g = gt + i;
    const int b = g >> 10, s0 = (g & 1023) << 4;
    const bool has_next = (i + 1 < TPB);
    const int gn = g + 1;
    const float* xn = x + (size_t)(gn >> 10) * (5 * 256 * SP) + ((gn & 1023) << 4) + r;

    f32x4 qacc[2] = {};
    f32x4 kacc[2][5] = {};
    f32x4 vacc[2][5] = {};
    float ld[2][8];
    f16x8 nxt[5];

    // ---- main GEMM over k, with embedded next-tile staging loads ----
#pragma unroll
    for (int k0 = 0; k0 < 8; ++k0) {
      // pack group issued 2 iterations ago (t = k0-2)
      if (has_next && k0 >= 2 && k0 <= 6) {
        f16x8 pk;
#pragma unroll
        for (int j = 0; j < 8; ++j) pk[j] = (f16)ld[k0 & 1][j];
        nxt[k0 - 2] = pk;
      }
      // issue loads for next tile, t = k0
      if (has_next && k0 < 5) {
#pragma unroll
        for (int j = 0; j < 8; ++j)
          ld[k0 & 1][j] = xn[(size_t)(k0 * 256 + 8 * q + j) * SP];
      }

      const int kk = (k0 << 5) + (g4 << 3);
      f16x8 a[5];
#pragma unroll
      for (int t = 0; t < 5; ++t) {
        const int byte = (t << 13) + (((c << 9) + (kk << 1)) ^ ((c & 7) << 4));
        a[t] = *(const f16x8*)(lr + byte);
      }
      const f16x8 fq0 = *(const f16x8*)(wqp0 + kk);
      const f16x8 fq1 = *(const f16x8*)(wqp1 + kk);
      const f16x8 fk0 = *(const f16x8*)(wkp0 + kk);
      const f16x8 fk1 = *(const f16x8*)(wkp1 + kk);
      const f16x8 fv0 = *(const f16x8*)(wvp0 + kk);
      const f16x8 fv1 = *(const f16x8*)(wvp1 + kk);

      qacc[0] = __builtin_amdgcn_mfma_f32_16x16x32_f16(a[0], fq0, qacc[0], 0, 0, 0);
      qacc[1] = __builtin_amdgcn_mfma_f32_16x16x32_f16(a[0], fq1, qacc[1], 0, 0, 0);
#pragma unroll
      for (int t = 0; t < 5; ++t) {
        kacc[0][t] = __builtin_amdgcn_mfma_f32_16x16x32_f16(a[t], fk0, kacc[0][t], 0, 0, 0);
        kacc[1][t] = __builtin_amdgcn_mfma_f32_16x16x32_f16(a[t], fk1, kacc[1][t], 0, 0, 0);
        vacc[0][t] = __builtin_amdgcn_mfma_f32_16x16x32_f16(a[t], fv0, vacc[0][t], 0, 0, 0);
        vacc[1][t] = __builtin_amdgcn_mfma_f32_16x16x32_f16(a[t], fv1, vacc[1][t], 0, 0, 0);
      }
    }

    __syncthreads();  // barrier_A: all xs reads done

    // write next tile's x into xs (frees nothing to wait on: packed already)
    if (has_next) {
#pragma unroll
      for (int t = 0; t < 5; ++t) {
        const int byte = (t << 13) + (((r << 9) + (q << 4)) ^ ((r & 7) << 4));
        *(f16x8*)((char*)xs + byte) = nxt[t];
      }
    }

    // ---- attention (in-register; C layout: col=c, rows 4g+r) ----
    f32x4 aout[2];
#pragma unroll
    for (int j = 0; j < 2; ++j) {
      f32x4 q4 = qacc[j];
#pragma unroll
      for (int rr = 0; rr < 4; ++rr) q4[rr] += bqv[j];

      f32x4 s[5];
#pragma unroll
      for (int t = 0; t < 5; ++t) {
        f32x4 k4 = kacc[j][t];
#pragma unroll
        for (int rr = 0; rr < 4; ++rr) k4[rr] += bkb[j];
        f32x4 p = q4 * k4;
#pragma unroll
        for (int rr = 0; rr < 4; ++rr) {
          float v = p[rr];
          v += __shfl_xor(v, 1);
          v += __shfl_xor(v, 2);
          v += __shfl_xor(v, 4);
          v += __shfl_xor(v, 8);
          s[t][rr] = v * 4.0f + pb[j][t];  // /temperature (=0.25) + pos_bias
        }
      }
      f32x4 m = s[0];
#pragma unroll
      for (int t = 1; t < 5; ++t)
#pragma unroll
        for (int rr = 0; rr < 4; ++rr) m[rr] = fmaxf(m[rr], s[t][rr]);
      f32x4 lsum = {};
#pragma unroll
      for (int t = 0; t < 5; ++t)
#pragma unroll
        for (int rr = 0; rr < 4; ++rr) { s[t][rr] = __expf(s[t][rr] - m[rr]); lsum[rr] += s[t][rr]; }
      f32x4 inv;
#pragma unroll
      for (int rr = 0; rr < 4; ++rr) inv[rr] = 1.0f / lsum[rr];
      f32x4 o = {};
#pragma unroll
      for (int t = 0; t < 5; ++t)
#pragma unroll
        for (int rr = 0; rr < 4; ++rr) o[rr] += s[t][rr] * inv[rr] * (vacc[j][t][rr] + bvb[j]);
      aout[j] = o;
    }

    // attn_out [16][256] fp16 -> as (same swizzle, no t offset)
#pragma unroll
    for (int j = 0; j < 2; ++j) {
      const int feat = (hA + j) * 16 + c;
#pragma unroll
      for (int rr = 0; rr < 4; ++rr) {
        const int row = (g4 << 2) + rr;
        const int byte = (((row << 9) + (feat << 1))) ^ ((row & 7) << 4);
        *(f16*)((char*)as + byte) = (f16)aout[j][rr];
      }
    }
    __syncthreads();  // barrier_B: attn-out visible; xs writes visible for next iter

    // ---- final projection: attn_out[16x256] @ Wp ----
    f32x4 facc[2] = {};
#pragma unroll
    for (int k0 = 0; k0 < 8; ++k0) {
      const int kk = (k0 << 5) + (g4 << 3);
      const int byte = (((c << 9) + (kk << 1)) ^ ((c & 7) << 4));
      const f16x8 af = *(const f16x8*)((const char*)as + byte);
      const f16x8 f0 = *(const f16x8*)(wpp0 + kk);
      const f16x8 f1 = *(const f16x8*)(wpp1 + kk);
      facc[0] = __builtin_amdgcn_mfma_f32_16x16x32_f16(af, f0, facc[0], 0, 0, 0);
      facc[1] = __builtin_amdgcn_mfma_f32_16x16x32_f16(af, f1, facc[1], 0, 0, 0);
    }

    // ---- store: out[b, dg, s0 + 4*g4 + rr] ----
#pragma unroll
    for (int j = 0; j < 2; ++j) {
      const int dg = (hA + j) * 16 + c;
      f32x4 vs = facc[j];
#pragma unroll
      for (int rr = 0; rr < 4; ++rr) vs[rr] += bpv[j];
      float* dst = out + ((size_t)b * 256 + dg) * SP + s0 + (g4 << 2);
      *(f32x4*)dst = vs;
    }
  }
}

extern "C" void kernel_launch(void* const* d_in, const int* in_sizes, int n_in,
                              void* d_out, int out_size, void* d_ws, size_t ws_size,
                              hipStream_t stream) {
  const float* x   = (const float*)d_in[0];
  const float* Wq  = (const float*)d_in[1];
  const float* bq  = (const float*)d_in[2];
  const float* Wkv = (const float*)d_in[3];
  const float* bkv = (const float*)d_in[4];
  const float* Wp  = (const float*)d_in[5];
  const float* bp  = (const float*)d_in[6];
  const float* pos = (const float*)d_in[7];

  f16* wqT  = (f16*)d_ws;            // 256*256
  f16* wkvT = wqT + 256 * 256;       // 512*256
  f16* wpT  = wkvT + 512 * 256;      // 256*256

  prep_weights<<<256, 512, 0, stream>>>(Wq, Wkv, Wp, wqT, wkvT, wpT);
  fused_attn<<<512, 512, 0, stream>>>(x, bq, bkv, bp, pos, wqT, wkvT, wpT,
                                      (float*)d_out);
}